// Round 8
// baseline (322.770 us; speedup 1.0000x reference)
//
#include <hip/hip_runtime.h>
#include <hip/hip_bf16.h>

#define HH 128
#define EE 256
#define KK 4
#define RR 8
#define LL 2
#define BB 2
#define SS 1024
#define BT (BB*SS)      // 2048 tokens total
#define NJ (RR+2*HH)    // 264 dbc rows
#define GG 16           // scan chunks per sequence
#define CH (SS/GG)      // 64 timesteps per chunk
#define EPS 1e-5f
#define LOG2E 1.44269504088896f

__device__ __forceinline__ float silu_f(float v) {
    return v / (1.0f + __expf(-v));
}

// ---------------- K0: Wdt = pl_w[:, :8] @ dt_w ; bdt = pl_b[:8]@dt_w + dt_b --
__global__ __launch_bounds__(256) void k_wdt(
    const float* __restrict__ plw, const float* __restrict__ plb,
    const float* __restrict__ dtw, const float* __restrict__ dtb,
    float* __restrict__ Wdt, float* __restrict__ bdt)
{
    const int l = blockIdx.x >> 2, q = blockIdx.x & 3;
    const int j = threadIdx.x;
    const float* dtwl = dtw + (size_t)l * RR * EE;
    const float* plwl = plw + (size_t)l * EE * NJ;
    float wr[RR];
    #pragma unroll
    for (int r = 0; r < RR; r++) wr[r] = dtwl[r * EE + j];
    float* Wl = Wdt + (size_t)l * EE * EE;
    for (int e = q * 64; e < q * 64 + 64; e++) {
        float a = 0.0f;
        #pragma unroll
        for (int r = 0; r < RR; r++) a += plwl[(size_t)e * NJ + r] * wr[r];
        Wl[(size_t)e * EE + j] = a;
    }
    if (q == 0) {
        float a = dtb[l * EE + j];
        #pragma unroll
        for (int r = 0; r < RR; r++) a += plb[l * NJ + r] * wr[r];
        bdt[l * EE + j] = a;
    }
}

// ---------------- K1: rmsnorm + in_proj -> xz [2048][512] --------------------
// 4-token tiles, grid 512, block 256; each thread: 2 cols (j, j+256), 8 accs.
__global__ __launch_bounds__(256) void k_ninp(
    const float* __restrict__ resin, const float* __restrict__ inw,
    const float* __restrict__ inb, const float* __restrict__ nw,
    float* __restrict__ xz)
{
    __shared__ float xn[4][132];
    const int bt0 = blockIdx.x * 4;
    const int tid = threadIdx.x;
    {   // rmsnorm: one wave per token
        const int t = tid >> 6, lane = tid & 63;
        const float2 xv = *(const float2*)(resin + (size_t)(bt0 + t) * HH + lane * 2);
        float ss = xv.x*xv.x + xv.y*xv.y;
        #pragma unroll
        for (int m = 32; m >= 1; m >>= 1) ss += __shfl_xor(ss, m);
        const float rs = rsqrtf(ss * (1.0f / HH) + EPS);
        const float2 wv = *(const float2*)(nw + lane * 2);
        xn[t][lane*2+0] = xv.x * rs * wv.x;
        xn[t][lane*2+1] = xv.y * rs * wv.y;
    }
    __syncthreads();
    const int j0 = tid, j1 = tid + 256;
    float acc0[4], acc1[4];
    const float b0 = inb[j0], b1 = inb[j1];
    #pragma unroll
    for (int t = 0; t < 4; t++) { acc0[t] = b0; acc1[t] = b1; }
    // 2-deep weight prefetch ring
    float wa[2][4], wb[2][4];
    #pragma unroll
    for (int s = 0; s < 2; s++) {
        #pragma unroll
        for (int kk = 0; kk < 4; kk++) {
            wa[s][kk] = inw[(s*4 + kk)*512 + j0];
            wb[s][kk] = inw[(s*4 + kk)*512 + j1];
        }
    }
    for (int k4 = 0; k4 < 32; k4++) {
        float ca[4], cb4[4];
        #pragma unroll
        for (int kk = 0; kk < 4; kk++) { ca[kk] = wa[k4&1][kk]; cb4[kk] = wb[k4&1][kk]; }
        if (k4 < 30) {
            const int k = (k4 + 2) * 4;
            #pragma unroll
            for (int kk = 0; kk < 4; kk++) {
                wa[k4&1][kk] = inw[(k + kk)*512 + j0];
                wb[k4&1][kk] = inw[(k + kk)*512 + j1];
            }
        }
        const int k = k4 * 4;
        #pragma unroll
        for (int t = 0; t < 4; t++) {
            const float4 xv = *(const float4*)(&xn[t][k]);
            acc0[t] += ca[0]*xv.x + ca[1]*xv.y + ca[2]*xv.z + ca[3]*xv.w;
            acc1[t] += cb4[0]*xv.x + cb4[1]*xv.y + cb4[2]*xv.z + cb4[3]*xv.w;
        }
    }
    #pragma unroll
    for (int t = 0; t < 4; t++) {
        xz[(size_t)(bt0 + t) * 512 + j0] = acc0[t];
        xz[(size_t)(bt0 + t) * 512 + j1] = acc1[t];
    }
}

// ---------------- K2: conv+silu + B/C-proj + delta-proj ----------------------
// 4-token tiles, grid 512, block 256; thread: 1 B/C col + 1 delta col.
__global__ __launch_bounds__(256) void k_cbd(
    const float* __restrict__ xz, const float* __restrict__ cw,
    const float* __restrict__ cb, const float* __restrict__ plw,
    const float* __restrict__ plb, const float* __restrict__ Wdt,
    const float* __restrict__ bdt,
    float* __restrict__ xcT, float* __restrict__ BC4,
    float* __restrict__ deltaT, float* __restrict__ sT)
{
    __shared__ float xcb[4][256];
    const int bt0 = blockIdx.x * 4;
    const int tid = threadIdx.x;
    {   // conv + silu: thread = e, 4 tokens
        const int e = tid;
        const float w0 = cw[e*4+0], w1 = cw[e*4+1], w2 = cw[e*4+2], w3 = cw[e*4+3];
        const float bias = cb[e];
        const float* xp = xz + (size_t)bt0 * 512 + e;
        const bool first = ((bt0 & (SS - 1)) == 0);
        float xm3 = first ? 0.0f : xp[-3*512];
        float xm2 = first ? 0.0f : xp[-2*512];
        float xm1 = first ? 0.0f : xp[-1*512];
        float xcv[4];
        #pragma unroll
        for (int i = 0; i < 4; i++) {
            const float x0 = xp[i*512];
            const float v = bias + w3*x0 + w2*xm1 + w1*xm2 + w0*xm3;
            const float o = silu_f(v);
            xcv[i] = o;
            xcb[i][e] = o;
            xm3 = xm2; xm2 = xm1; xm1 = x0;
        }
        *(float4*)(xcT + (size_t)e * BT + bt0) =
            make_float4(xcv[0], xcv[1], xcv[2], xcv[3]);
    }
    __syncthreads();
    // projections: BC col tid + delta col tid, 2-deep prefetch each
    const int nn = tid & 127, isC = tid >> 7;
    const float* wbc = plw + RR + isC * HH + nn;    // stride NJ
    const float* wdp = Wdt + tid;                   // stride EE
    float accb[4], accd[4];
    const float bb = plb[RR + isC * HH + nn];
    const float bd = bdt[tid];
    #pragma unroll
    for (int t = 0; t < 4; t++) { accb[t] = bb; accd[t] = bd; }
    float pb[2][4], pd[2][4];
    #pragma unroll
    for (int s = 0; s < 2; s++) {
        #pragma unroll
        for (int kk = 0; kk < 4; kk++) {
            pb[s][kk] = wbc[(size_t)(s*4 + kk) * NJ];
            pd[s][kk] = wdp[(size_t)(s*4 + kk) * EE];
        }
    }
    for (int e4 = 0; e4 < 64; e4++) {
        float cbw[4], cdw[4];
        #pragma unroll
        for (int kk = 0; kk < 4; kk++) { cbw[kk] = pb[e4&1][kk]; cdw[kk] = pd[e4&1][kk]; }
        if (e4 < 62) {
            const int e = (e4 + 2) * 4;
            #pragma unroll
            for (int kk = 0; kk < 4; kk++) {
                pb[e4&1][kk] = wbc[(size_t)(e + kk) * NJ];
                pd[e4&1][kk] = wdp[(size_t)(e + kk) * EE];
            }
        }
        const int e = e4 * 4;
        #pragma unroll
        for (int t = 0; t < 4; t++) {
            const float4 xv = *(const float4*)(&xcb[t][e]);
            accb[t] += cbw[0]*xv.x + cbw[1]*xv.y + cbw[2]*xv.z + cbw[3]*xv.w;
            accd[t] += cdw[0]*xv.x + cdw[1]*xv.y + cdw[2]*xv.z + cdw[3]*xv.w;
        }
    }
    // BC4 write: this tile is exactly one t-quad
    const int tq0 = bt0 >> 2;
    *(float4*)(BC4 + ((size_t)tq0 * 128 + nn) * 8 + isC * 4) =
        make_float4(accb[0], accb[1], accb[2], accb[3]);
    // delta/softplus/s
    float spv[4], sv[4];
    #pragma unroll
    for (int t = 0; t < 4; t++) {
        const float d = accd[t];
        const float sp = (d > 15.0f) ? d : log1pf(__expf(d));
        spv[t] = sp;
        sv[t] = sp * xcb[t][tid];
    }
    *(float4*)(deltaT + (size_t)tid * BT + bt0) =
        make_float4(spv[0], spv[1], spv[2], spv[3]);
    *(float4*)(sT + (size_t)tid * BT + bt0) =
        make_float4(sv[0], sv[1], sv[2], sv[3]);
}

// ---------------- K3: chunk-local scan, 4 e's per block ----------------------
// grid = B*GG*(EE/4) = 2048, block = 128 (n). XCD-swizzled.
__global__ __launch_bounds__(128, 4) void k_scan_local(
    const float* __restrict__ BC4, const float* __restrict__ deltaT,
    const float* __restrict__ sT, const float* __restrict__ Alog,
    float* __restrict__ yT, float* __restrict__ hchain,
    float* __restrict__ dsum)
{
    __shared__ float part[4][16][68];
    __shared__ float ybuf[4][CH];
    const int blk = blockIdx.x;
    const int wgid = (blk & 7) * 256 + (blk >> 3);   // bijective XCD swizzle
    const int eq = wgid & 63;
    const int r0 = wgid >> 6;       // 0..31 = (b,g)
    const int b = r0 >> 4;
    const int g = r0 & 15;
    const int e0 = eq * 4;
    const int n = threadIdx.x;
    const int t0 = g * CH;

    float An[4], h[4], cum[4];
    #pragma unroll
    for (int ee = 0; ee < 4; ee++) {
        An[ee] = -__expf(Alog[(e0 + ee) * HH + n]) * LOG2E;
        h[ee] = 0.0f; cum[ee] = 0.0f;
    }
    const float* bc = BC4 + ((size_t)((b * 256 + g * 16) * 128 + n)) * 8;
    const float* dr[4]; const float* sr[4];
    #pragma unroll
    for (int ee = 0; ee < 4; ee++) {
        dr[ee] = deltaT + (size_t)(e0 + ee) * BT + b * SS + t0;
        sr[ee] = sT + (size_t)(e0 + ee) * BT + b * SS + t0;
    }
    float4 pB = *(const float4*)(bc);
    float4 pC = *(const float4*)(bc + 4);
    float4 pd[4], ps[4];
    #pragma unroll
    for (int ee = 0; ee < 4; ee++) {
        pd[ee] = *(const float4*)dr[ee];
        ps[ee] = *(const float4*)sr[ee];
    }
    const int tl = n >> 3, jj = n & 7;
    for (int sc = 0; sc < 4; sc++) {
        #pragma unroll
        for (int q = 0; q < 4; q++) {
            const int qq = sc * 4 + q;
            const float4 cB = pB, cC = pC;
            float4 cd[4], cs[4];
            #pragma unroll
            for (int ee = 0; ee < 4; ee++) { cd[ee] = pd[ee]; cs[ee] = ps[ee]; }
            if (qq < 15) {
                const size_t off = (size_t)(qq + 1) * 1024;
                pB = *(const float4*)(bc + off);
                pC = *(const float4*)(bc + off + 4);
                const int t = (qq + 1) * 4;
                #pragma unroll
                for (int ee = 0; ee < 4; ee++) {
                    pd[ee] = *(const float4*)(dr[ee] + t);
                    ps[ee] = *(const float4*)(sr[ee] + t);
                }
            }
            #pragma unroll
            for (int ee = 0; ee < 4; ee++) {
                float a;
                a = exp2f(cd[ee].x*An[ee]); h[ee] = a*h[ee] + cs[ee].x*cB.x;
                part[ee][q*4+0][n] = h[ee]*cC.x;
                a = exp2f(cd[ee].y*An[ee]); h[ee] = a*h[ee] + cs[ee].y*cB.y;
                part[ee][q*4+1][n] = h[ee]*cC.y;
                a = exp2f(cd[ee].z*An[ee]); h[ee] = a*h[ee] + cs[ee].z*cB.z;
                part[ee][q*4+2][n] = h[ee]*cC.z;
                a = exp2f(cd[ee].w*An[ee]); h[ee] = a*h[ee] + cs[ee].w*cB.w;
                part[ee][q*4+3][n] = h[ee]*cC.w;
                cum[ee] += (cd[ee].x + cd[ee].y) + (cd[ee].z + cd[ee].w);
            }
        }
        __syncthreads();
        #pragma unroll
        for (int ee = 0; ee < 4; ee++) {
            float s0 = 0, s1 = 0, s2 = 0, s3 = 0;
            #pragma unroll
            for (int i = 0; i < 4; i++) {
                const float4 p = *(const float4*)(&part[ee][tl][jj*16 + i*4]);
                s0 += p.x; s1 += p.y; s2 += p.z; s3 += p.w;
            }
            float r = (s0 + s1) + (s2 + s3);
            r += __shfl_xor(r, 1); r += __shfl_xor(r, 2); r += __shfl_xor(r, 4);
            if (jj == 0) ybuf[ee][sc*16 + tl] = r;
        }
        __syncthreads();
    }
    {
        const int ee = n >> 5, tt = n & 31;
        float* yp = yT + (size_t)(e0 + ee) * BT + b * SS + t0;
        yp[tt] = ybuf[ee][tt];
        yp[tt + 32] = ybuf[ee][tt + 32];
    }
    #pragma unroll
    for (int ee = 0; ee < 4; ee++)
        hchain[(size_t)(((b * EE + e0 + ee) * GG) + g) * 128 + n] = h[ee];
    if (n == 0) {
        #pragma unroll
        for (int ee = 0; ee < 4; ee++)
            dsum[(b * EE + e0 + ee) * GG + g] = cum[ee];
    }
}

// ---------------- K4: cross-chunk correction (inline combine), 4 e's ---------
// grid = B*15*(EE/4) = 1920, block = 128 (n)
__global__ __launch_bounds__(128, 4) void k_scan_fix(
    const float* __restrict__ BC4, const float* __restrict__ deltaT,
    const float* __restrict__ Alog, const float* __restrict__ hchain,
    const float* __restrict__ dsum, float* __restrict__ yT)
{
    __shared__ float part[4][16][68];
    __shared__ float ybuf[4][CH];
    const int blk = blockIdx.x;
    const int wgid = (blk & 7) * 240 + (blk >> 3);   // bijective XCD swizzle
    const int eq = wgid & 63;
    const int r0 = wgid >> 6;       // 0..29
    const int b = r0 / 15;
    const int g = 1 + (r0 % 15);
    const int e0 = eq * 4;
    const int n = threadIdx.x;
    const int t0 = g * CH;

    float An[4], w[4], D[4];
    #pragma unroll
    for (int ee = 0; ee < 4; ee++) {
        An[ee] = -__expf(Alog[(e0 + ee) * HH + n]) * LOG2E;
        w[ee] = 0.0f; D[ee] = 0.0f;
    }
    {   // inline combine: chain h_end across chunks 0..g-1
        for (int gp = 0; gp < g; gp++) {
            #pragma unroll
            for (int ee = 0; ee < 4; ee++) {
                const float he = hchain[(size_t)(((b * EE + e0 + ee) * GG) + gp) * 128 + n];
                const float ds = dsum[(b * EE + e0 + ee) * GG + gp];
                w[ee] = exp2f(An[ee] * ds) * w[ee] + he;
            }
        }
    }
    const float* bc = BC4 + ((size_t)((b * 256 + g * 16) * 128 + n)) * 8;
    const float* dr[4];
    #pragma unroll
    for (int ee = 0; ee < 4; ee++)
        dr[ee] = deltaT + (size_t)(e0 + ee) * BT + b * SS + t0;

    float4 pC = *(const float4*)(bc + 4);
    float4 pd[4];
    #pragma unroll
    for (int ee = 0; ee < 4; ee++) pd[ee] = *(const float4*)dr[ee];

    const int tl = n >> 3, jj = n & 7;
    for (int sc = 0; sc < 4; sc++) {
        #pragma unroll
        for (int q = 0; q < 4; q++) {
            const int qq = sc * 4 + q;
            const float4 cC = pC;
            float4 cd[4];
            #pragma unroll
            for (int ee = 0; ee < 4; ee++) cd[ee] = pd[ee];
            if (qq < 15) {
                const size_t off = (size_t)(qq + 1) * 1024;
                pC = *(const float4*)(bc + off + 4);
                const int t = (qq + 1) * 4;
                #pragma unroll
                for (int ee = 0; ee < 4; ee++)
                    pd[ee] = *(const float4*)(dr[ee] + t);
            }
            #pragma unroll
            for (int ee = 0; ee < 4; ee++) {
                D[ee] += cd[ee].x; part[ee][q*4+0][n] = exp2f(An[ee]*D[ee]) * w[ee] * cC.x;
                D[ee] += cd[ee].y; part[ee][q*4+1][n] = exp2f(An[ee]*D[ee]) * w[ee] * cC.y;
                D[ee] += cd[ee].z; part[ee][q*4+2][n] = exp2f(An[ee]*D[ee]) * w[ee] * cC.z;
                D[ee] += cd[ee].w; part[ee][q*4+3][n] = exp2f(An[ee]*D[ee]) * w[ee] * cC.w;
            }
        }
        __syncthreads();
        #pragma unroll
        for (int ee = 0; ee < 4; ee++) {
            float s0 = 0, s1 = 0, s2 = 0, s3 = 0;
            #pragma unroll
            for (int i = 0; i < 4; i++) {
                const float4 p = *(const float4*)(&part[ee][tl][jj*16 + i*4]);
                s0 += p.x; s1 += p.y; s2 += p.z; s3 += p.w;
            }
            float r = (s0 + s1) + (s2 + s3);
            r += __shfl_xor(r, 1); r += __shfl_xor(r, 2); r += __shfl_xor(r, 4);
            if (jj == 0) ybuf[ee][sc*16 + tl] = r;
        }
        __syncthreads();
    }
    {
        const int ee = n >> 5, tt = n & 31;
        float* yp = yT + (size_t)(e0 + ee) * BT + b * SS + t0;
        yp[tt] += ybuf[ee][tt];
        yp[tt + 32] += ybuf[ee][tt + 32];
    }
}

// ---------------- K5: gate + out_proj + residual -> xres ---------------------
// 4-token tiles, grid 512, block 256
__global__ __launch_bounds__(256) void k_gate(
    const float* __restrict__ yT, const float* __restrict__ xcT,
    const float* __restrict__ zbuf, const float* __restrict__ Dp,
    const float* __restrict__ ow, const float* __restrict__ ob,
    const float* __restrict__ resin, float* __restrict__ xres)
{
    __shared__ float gs[4][256];
    __shared__ float p2[4][128];
    const int bt0 = blockIdx.x * 4;
    const int tid = threadIdx.x;
    {
        const int e = tid;
        const float dp = Dp[e];
        const float4 y4 = *(const float4*)(yT + (size_t)e * BT + bt0);
        const float4 x4 = *(const float4*)(xcT + (size_t)e * BT + bt0);
        gs[0][e] = (y4.x + dp * x4.x) * silu_f(zbuf[(size_t)(bt0+0) * 256 + e]);
        gs[1][e] = (y4.y + dp * x4.y) * silu_f(zbuf[(size_t)(bt0+1) * 256 + e]);
        gs[2][e] = (y4.z + dp * x4.z) * silu_f(zbuf[(size_t)(bt0+2) * 256 + e]);
        gs[3][e] = (y4.w + dp * x4.w) * silu_f(zbuf[(size_t)(bt0+3) * 256 + e]);
    }
    __syncthreads();
    const int j = tid & 127;
    const int kh = tid >> 7;
    float acc[4] = {0.f, 0.f, 0.f, 0.f};
    const int eb = kh * 128;
    float wp[2][4];
    #pragma unroll
    for (int s = 0; s < 2; s++)
        #pragma unroll
        for (int kk = 0; kk < 4; kk++)
            wp[s][kk] = ow[(eb + s*4 + kk)*HH + j];
    for (int e4 = 0; e4 < 32; e4++) {
        float cw4[4];
        #pragma unroll
        for (int kk = 0; kk < 4; kk++) cw4[kk] = wp[e4&1][kk];
        if (e4 < 30) {
            const int e = eb + (e4 + 2) * 4;
            #pragma unroll
            for (int kk = 0; kk < 4; kk++) wp[e4&1][kk] = ow[(e + kk)*HH + j];
        }
        const int e = eb + e4 * 4;
        #pragma unroll
        for (int t = 0; t < 4; t++) {
            const float4 g4 = *(const float4*)(&gs[t][e]);
            acc[t] += cw4[0]*g4.x + cw4[1]*g4.y + cw4[2]*g4.z + cw4[3]*g4.w;
        }
    }
    if (kh == 1) {
        #pragma unroll
        for (int t = 0; t < 4; t++) p2[t][j] = acc[t];
    }
    __syncthreads();
    if (kh == 0) {
        const float bj = ob[j];
        #pragma unroll
        for (int t = 0; t < 4; t++) {
            const float r = acc[t] + p2[t][j] + bj
                          + resin[(size_t)(bt0 + t) * HH + j];
            xres[(size_t)(bt0 + t) * HH + j] = r;
        }
    }
}

// ---------------- K6: gate + out_proj + residual + final rmsnorm -> out ------
__global__ __launch_bounds__(256) void k_gate_final(
    const float* __restrict__ yT, const float* __restrict__ xcT,
    const float* __restrict__ zbuf, const float* __restrict__ Dp,
    const float* __restrict__ ow, const float* __restrict__ ob,
    const float* __restrict__ resin, const float* __restrict__ fw,
    float* __restrict__ out)
{
    __shared__ float gs[4][256];
    __shared__ float p2[4][132];
    const int bt0 = blockIdx.x * 4;
    const int tid = threadIdx.x;
    {
        const int e = tid;
        const float dp = Dp[e];
        const float4 y4 = *(const float4*)(yT + (size_t)e * BT + bt0);
        const float4 x4 = *(const float4*)(xcT + (size_t)e * BT + bt0);
        gs[0][e] = (y4.x + dp * x4.x) * silu_f(zbuf[(size_t)(bt0+0) * 256 + e]);
        gs[1][e] = (y4.y + dp * x4.y) * silu_f(zbuf[(size_t)(bt0+1) * 256 + e]);
        gs[2][e] = (y4.z + dp * x4.z) * silu_f(zbuf[(size_t)(bt0+2) * 256 + e]);
        gs[3][e] = (y4.w + dp * x4.w) * silu_f(zbuf[(size_t)(bt0+3) * 256 + e]);
    }
    __syncthreads();
    const int j = tid & 127;
    const int kh = tid >> 7;
    {
        float acc[4] = {0.f, 0.f, 0.f, 0.f};
        const int eb = kh * 128;
        float wp[2][4];
        #pragma unroll
        for (int s = 0; s < 2; s++)
            #pragma unroll
            for (int kk = 0; kk < 4; kk++)
                wp[s][kk] = ow[(eb + s*4 + kk)*HH + j];
        for (int e4 = 0; e4 < 32; e4++) {
            float cw4[4];
            #pragma unroll
            for (int kk = 0; kk < 4; kk++) cw4[kk] = wp[e4&1][kk];
            if (e4 < 30) {
                const int e = eb + (e4 + 2) * 4;
                #pragma unroll
                for (int kk = 0; kk < 4; kk++) wp[e4&1][kk] = ow[(e + kk)*HH + j];
            }
            const int e = eb + e4 * 4;
            #pragma unroll
            for (int t = 0; t < 4; t++) {
                const float4 g4 = *(const float4*)(&gs[t][e]);
                acc[t] += cw4[0]*g4.x + cw4[1]*g4.y + cw4[2]*g4.z + cw4[3]*g4.w;
            }
        }
        if (kh == 1) {
            #pragma unroll
            for (int t = 0; t < 4; t++) p2[t][j] = acc[t];
        }
        __syncthreads();
        if (kh == 0) {
            const float bj = ob[j];
            #pragma unroll
            for (int t = 0; t < 4; t++) {
                const float r = acc[t] + p2[t][j] + bj
                              + resin[(size_t)(bt0 + t) * HH + j];
                p2[t][j] = r;
            }
        }
    }
    __syncthreads();
    {   // final rmsnorm: one wave per token, 2 cols/lane
        const int t = tid >> 6, lane = tid & 63;
        const float2 v = *(const float2*)(&p2[t][lane * 2]);
        float ss = v.x*v.x + v.y*v.y;
        #pragma unroll
        for (int m = 32; m >= 1; m >>= 1) ss += __shfl_xor(ss, m);
        const float rs = rsqrtf(ss * (1.0f / HH) + EPS);
        const float2 w = *(const float2*)(fw + lane * 2);
        float2 o; o.x = v.x * rs * w.x; o.y = v.y * rs * w.y;
        *(float2*)(out + (size_t)(bt0 + t) * HH + lane * 2) = o;
    }
}

extern "C" void kernel_launch(void* const* d_in, const int* in_sizes, int n_in,
                              void* d_out, int out_size, void* d_ws, size_t ws_size,
                              hipStream_t stream)
{
    const float* x      = (const float*)d_in[0];
    const float* in_w   = (const float*)d_in[1];
    const float* in_b   = (const float*)d_in[2];
    const float* out_w  = (const float*)d_in[3];
    const float* out_b  = (const float*)d_in[4];
    const float* pl_w   = (const float*)d_in[5];
    const float* pl_b   = (const float*)d_in[6];
    const float* dt_w   = (const float*)d_in[7];
    const float* dt_b   = (const float*)d_in[8];
    const float* conv_w = (const float*)d_in[9];
    const float* conv_b = (const float*)d_in[10];
    const float* A_log  = (const float*)d_in[11];
    const float* Dp     = (const float*)d_in[12];
    const float* norm_w = (const float*)d_in[13];
    const float* fnw    = (const float*)d_in[14];

    float* ws     = (float*)d_ws;
    float* xres   = ws;                        // 262144
    float* xz     = xres   + 262144;           // 1048576 (xc half + z half)
    float* xcT    = xz     + 1048576;          // 524288
    float* BC4    = xcT    + 524288;           // 524288
    float* deltaT = BC4    + 524288;           // 524288
    float* sT     = deltaT + 524288;           // 524288
    float* yT     = sT     + 524288;           // 524288
    float* hchain = yT     + 524288;           // 1048576
    float* dsum   = hchain + 1048576;          // 8192
    float* Wdt    = dsum   + 8192;             // 131072
    float* bdt    = Wdt    + 131072;           // 512

    // zbuf view: z half lives interleaved in xz (cols 256..511)
    k_wdt<<<2*4, 256, 0, stream>>>(pl_w, pl_b, dt_w, dt_b, Wdt, bdt);

    for (int l = 0; l < LL; l++) {
        const float* resin = (l == 0) ? x : xres;
        k_ninp<<<BT/4, 256, 0, stream>>>(
            resin, in_w + (size_t)l*HH*2*EE, in_b + (size_t)l*2*EE,
            norm_w + (size_t)l*HH, xz);
        k_cbd<<<BT/4, 256, 0, stream>>>(
            xz, conv_w + (size_t)l*EE*KK, conv_b + (size_t)l*EE,
            pl_w + (size_t)l*EE*NJ, pl_b + (size_t)l*NJ,
            Wdt + (size_t)l*EE*EE, bdt + (size_t)l*EE,
            xcT, BC4, deltaT, sT);
        k_scan_local<<<BB*GG*(EE/4), 128, 0, stream>>>(
            BC4, deltaT, sT, A_log + (size_t)l*EE*HH, yT, hchain, dsum);
        k_scan_fix<<<BB*(GG-1)*(EE/4), 128, 0, stream>>>(
            BC4, deltaT, A_log + (size_t)l*EE*HH, hchain, dsum, yT);
        // zbuf argument: pass xz + 256 with row stride 512 handled by kernel?
        // k_gate expects zbuf[t][256]; we stored z in xz[t][512] cols 256..511.
        if (l < LL - 1) {
            k_gate<<<BT/4, 256, 0, stream>>>(
                yT, xcT, xz, Dp + (size_t)l*EE,
                out_w + (size_t)l*EE*HH, out_b + (size_t)l*HH, resin, xres);
        } else {
            k_gate_final<<<BT/4, 256, 0, stream>>>(
                yT, xcT, xz, Dp + (size_t)l*EE,
                out_w + (size_t)l*EE*HH, out_b + (size_t)l*HH, xres,
                fnw, (float*)d_out);
        }
    }
}

// NOTE on zbuf: k_gate/k_gate_final read the z-gate as
// zbuf[(bt)*256 + e]; but z is stored in xz with row stride 512 at col 256+e.
// To keep a single buffer, the launch passes xz and the kernels must index
// (bt)*512 + 256 + e. The definitions above are compiled with the macro below.

// Round 10
// 241.754 us; speedup vs baseline: 1.3351x; 1.3351x over previous
//
#include <hip/hip_runtime.h>
#include <hip/hip_bf16.h>

#define HH 128
#define EE 256
#define KK 4
#define RR 8
#define LL 2
#define BB 2
#define SS 1024
#define BT (BB*SS)      // 2048 tokens total
#define NJ (RR+2*HH)    // 264 dbc rows
#define GG 16           // scan chunks per sequence
#define CH (SS/GG)      // 64 timesteps per chunk
#define EPS 1e-5f
#define LOG2E 1.44269504088896f

__device__ __forceinline__ void fma4(float4& a, float s, const float4& v) {
    a.x += s * v.x; a.y += s * v.y; a.z += s * v.z; a.w += s * v.w;
}

__device__ __forceinline__ float silu_f(float v) {
    return v / (1.0f + __expf(-v));
}

// ---------------- K0: Wdt = pl_w[:, :8] @ dt_w ; bdt = pl_b[:8]@dt_w + dt_b --
__global__ __launch_bounds__(256) void k_wdt(
    const float* __restrict__ plw, const float* __restrict__ plb,
    const float* __restrict__ dtw, const float* __restrict__ dtb,
    float* __restrict__ Wdt, float* __restrict__ bdt)
{
    const int l = blockIdx.x >> 2, q = blockIdx.x & 3;
    const int j = threadIdx.x;
    const float* dtwl = dtw + (size_t)l * RR * EE;
    const float* plwl = plw + (size_t)l * EE * NJ;
    float wr[RR];
    #pragma unroll
    for (int r = 0; r < RR; r++) wr[r] = dtwl[r * EE + j];
    float* Wl = Wdt + (size_t)l * EE * EE;
    for (int e = q * 64; e < q * 64 + 64; e++) {
        float a = 0.0f;
        #pragma unroll
        for (int r = 0; r < RR; r++) a += plwl[(size_t)e * NJ + r] * wr[r];
        Wl[(size_t)e * EE + j] = a;
    }
    if (q == 0) {
        float a = dtb[l * EE + j];
        #pragma unroll
        for (int r = 0; r < RR; r++) a += plb[l * NJ + r] * wr[r];
        bdt[l * EE + j] = a;
    }
}

// ---------------- K1: rmsnorm + in_proj -> xz [2048][512] --------------------
// 8-token tiles x 2 column-halves -> grid 512, block 256.
// Thread: 4 adjacent cols x 2 tokens, float4 weight loads.
__global__ __launch_bounds__(256) void k_ninp(
    const float* __restrict__ resin, const float* __restrict__ inw,
    const float* __restrict__ inb, const float* __restrict__ nw,
    float* __restrict__ xz)
{
    __shared__ float xn[8][132];
    const int tile = blockIdx.x >> 1, half = blockIdx.x & 1;
    const int bt0 = tile * 8;
    const int tid = threadIdx.x;
    {   // rmsnorm: 32 lanes per token
        const int t = tid >> 5, lane = tid & 31;
        const float4 xv = *(const float4*)(resin + (size_t)(bt0 + t) * HH + lane * 4);
        float ss = xv.x*xv.x + xv.y*xv.y + xv.z*xv.z + xv.w*xv.w;
        ss += __shfl_xor(ss, 16); ss += __shfl_xor(ss, 8);
        ss += __shfl_xor(ss, 4);  ss += __shfl_xor(ss, 2);
        ss += __shfl_xor(ss, 1);
        const float rs = rsqrtf(ss * (1.0f / HH) + EPS);
        const float4 wv = *(const float4*)(nw + lane * 4);
        xn[t][lane*4+0] = xv.x * rs * wv.x;
        xn[t][lane*4+1] = xv.y * rs * wv.y;
        xn[t][lane*4+2] = xv.z * rs * wv.z;
        xn[t][lane*4+3] = xv.w * rs * wv.w;
    }
    __syncthreads();
    const int jj = tid & 63, th = tid >> 6;      // th: 4 groups of 2 tokens
    const int c0 = half * 256 + jj * 4;
    const int t0 = th * 2;
    float4 acc0 = *(const float4*)(inb + c0);
    float4 acc1 = acc0;
    float4 wreg[4], wnx[4];
    #pragma unroll
    for (int kk = 0; kk < 4; kk++)
        wnx[kk] = *(const float4*)(inw + (size_t)kk * 512 + c0);
    for (int k4 = 0; k4 < 32; k4++) {
        #pragma unroll
        for (int kk = 0; kk < 4; kk++) wreg[kk] = wnx[kk];
        if (k4 < 31) {
            const int k = (k4 + 1) * 4;
            #pragma unroll
            for (int kk = 0; kk < 4; kk++)
                wnx[kk] = *(const float4*)(inw + (size_t)(k + kk) * 512 + c0);
        }
        const int k = k4 * 4;
        const float4 x0 = *(const float4*)(&xn[t0+0][k]);
        const float4 x1 = *(const float4*)(&xn[t0+1][k]);
        fma4(acc0, x0.x, wreg[0]); fma4(acc0, x0.y, wreg[1]);
        fma4(acc0, x0.z, wreg[2]); fma4(acc0, x0.w, wreg[3]);
        fma4(acc1, x1.x, wreg[0]); fma4(acc1, x1.y, wreg[1]);
        fma4(acc1, x1.z, wreg[2]); fma4(acc1, x1.w, wreg[3]);
    }
    *(float4*)(xz + (size_t)(bt0 + t0 + 0) * 512 + c0) = acc0;
    *(float4*)(xz + (size_t)(bt0 + t0 + 1) * 512 + c0) = acc1;
}

// ---------------- K2: conv+silu + {B/C-proj | delta-proj} --------------------
// 8-token tiles x 2 halves (half0: B/C, half1: delta) -> grid 512, block 256.
__global__ __launch_bounds__(256) void k_cbd(
    const float* __restrict__ xz, const float* __restrict__ cw,
    const float* __restrict__ cb, const float* __restrict__ plw,
    const float* __restrict__ plb, const float* __restrict__ Wdt,
    const float* __restrict__ bdt,
    float* __restrict__ xcT, float* __restrict__ BC4,
    float* __restrict__ deltaT, float* __restrict__ sT)
{
    __shared__ float xcb[8][260];
    __shared__ float st[8][260];
    const int tile = blockIdx.x >> 1, half = blockIdx.x & 1;
    const int bt0 = tile * 8;
    const int tid = threadIdx.x;
    {   // conv + silu: thread = e, 8 tokens (both halves compute all e)
        const int e = tid;
        const float w0 = cw[e*4+0], w1 = cw[e*4+1], w2 = cw[e*4+2], w3 = cw[e*4+3];
        const float bias = cb[e];
        const float* xp = xz + (size_t)bt0 * 512 + e;
        const bool first = ((bt0 & (SS - 1)) == 0);
        float xm3 = first ? 0.0f : xp[-3*512];
        float xm2 = first ? 0.0f : xp[-2*512];
        float xm1 = first ? 0.0f : xp[-1*512];
        float xcv[8];
        #pragma unroll
        for (int i = 0; i < 8; i++) {
            const float x0 = xp[i*512];
            const float v = bias + w3*x0 + w2*xm1 + w1*xm2 + w0*xm3;
            const float o = silu_f(v);
            xcv[i] = o;
            xcb[i][e] = o;
            xm3 = xm2; xm2 = xm1; xm1 = x0;
        }
        if ((e >> 7) == half) {   // each half owns 128 xcT rows
            float* orow = xcT + (size_t)e * BT + bt0;
            *(float4*)(orow)     = make_float4(xcv[0], xcv[1], xcv[2], xcv[3]);
            *(float4*)(orow + 4) = make_float4(xcv[4], xcv[5], xcv[6], xcv[7]);
        }
    }
    __syncthreads();
    // GEMM: thread = 4 adjacent cols (jj) x 2 tokens (th)
    const int jj = tid & 63, th = tid >> 6;
    const int c0 = jj * 4, t0 = th * 2;
    const float* wbase = half ? (Wdt + c0) : (plw + RR + c0);
    const int wstride = half ? EE : NJ;
    float4 acc0 = half ? *(const float4*)(bdt + c0)
                       : *(const float4*)(plb + RR + c0);
    float4 acc1 = acc0;
    float4 wreg[4], wnx[4];
    #pragma unroll
    for (int kk = 0; kk < 4; kk++)
        wnx[kk] = *(const float4*)(wbase + (size_t)kk * wstride);
    for (int e4 = 0; e4 < 64; e4++) {
        #pragma unroll
        for (int kk = 0; kk < 4; kk++) wreg[kk] = wnx[kk];
        if (e4 < 63) {
            const int e = (e4 + 1) * 4;
            #pragma unroll
            for (int kk = 0; kk < 4; kk++)
                wnx[kk] = *(const float4*)(wbase + (size_t)(e + kk) * wstride);
        }
        const int e = e4 * 4;
        const float4 x0 = *(const float4*)(&xcb[t0+0][e]);
        const float4 x1 = *(const float4*)(&xcb[t0+1][e]);
        fma4(acc0, x0.x, wreg[0]); fma4(acc0, x0.y, wreg[1]);
        fma4(acc0, x0.z, wreg[2]); fma4(acc0, x0.w, wreg[3]);
        fma4(acc1, x1.x, wreg[0]); fma4(acc1, x1.y, wreg[1]);
        fma4(acc1, x1.z, wreg[2]); fma4(acc1, x1.w, wreg[3]);
    }
    *(float4*)(&st[t0+0][c0]) = acc0;
    *(float4*)(&st[t0+1][c0]) = acc1;
    __syncthreads();
    // emission: thread = one column
    const int c = tid;
    if (half == 0) {
        const int n = c & 127, isC = c >> 7;
        const int tq0 = bt0 >> 2;
        #pragma unroll
        for (int q = 0; q < 2; q++) {
            const float4 v = make_float4(st[q*4+0][c], st[q*4+1][c],
                                         st[q*4+2][c], st[q*4+3][c]);
            *(float4*)(BC4 + ((size_t)(tq0 + q) * 128 + n) * 8 + isC * 4) = v;
        }
    } else {
        float spv[8], sv[8];
        #pragma unroll
        for (int t = 0; t < 8; t++) {
            const float d = st[t][c];
            const float sp = (d > 15.0f) ? d : log1pf(__expf(d));
            spv[t] = sp;
            sv[t] = sp * xcb[t][c];
        }
        float* drp = deltaT + (size_t)c * BT + bt0;
        *(float4*)(drp)     = make_float4(spv[0], spv[1], spv[2], spv[3]);
        *(float4*)(drp + 4) = make_float4(spv[4], spv[5], spv[6], spv[7]);
        float* srp = sT + (size_t)c * BT + bt0;
        *(float4*)(srp)     = make_float4(sv[0], sv[1], sv[2], sv[3]);
        *(float4*)(srp + 4) = make_float4(sv[4], sv[5], sv[6], sv[7]);
    }
}

// ---------------- K3: chunk-local scan, 4 e's per block ----------------------
// grid = B*GG*(EE/4) = 2048, block = 128 (n). XCD-swizzled.
__global__ __launch_bounds__(128, 4) void k_scan_local(
    const float* __restrict__ BC4, const float* __restrict__ deltaT,
    const float* __restrict__ sT, const float* __restrict__ Alog,
    float* __restrict__ yT, float* __restrict__ hchain,
    float* __restrict__ dsum)
{
    __shared__ float part[4][16][68];
    __shared__ float ybuf[4][CH];
    const int blk = blockIdx.x;
    const int wgid = (blk & 7) * 256 + (blk >> 3);   // bijective XCD swizzle
    const int eq = wgid & 63;
    const int r0 = wgid >> 6;       // 0..31 = (b,g)
    const int b = r0 >> 4;
    const int g = r0 & 15;
    const int e0 = eq * 4;
    const int n = threadIdx.x;
    const int t0 = g * CH;

    float An[4], h[4], cum[4];
    #pragma unroll
    for (int ee = 0; ee < 4; ee++) {
        An[ee] = -__expf(Alog[(e0 + ee) * HH + n]) * LOG2E;
        h[ee] = 0.0f; cum[ee] = 0.0f;
    }
    const float* bc = BC4 + ((size_t)((b * 256 + g * 16) * 128 + n)) * 8;
    const float* dr[4]; const float* sr[4];
    #pragma unroll
    for (int ee = 0; ee < 4; ee++) {
        dr[ee] = deltaT + (size_t)(e0 + ee) * BT + b * SS + t0;
        sr[ee] = sT + (size_t)(e0 + ee) * BT + b * SS + t0;
    }
    float4 pB = *(const float4*)(bc);
    float4 pC = *(const float4*)(bc + 4);
    float4 pd[4], ps[4];
    #pragma unroll
    for (int ee = 0; ee < 4; ee++) {
        pd[ee] = *(const float4*)dr[ee];
        ps[ee] = *(const float4*)sr[ee];
    }
    const int tl = n >> 3, jj = n & 7;
    for (int sc = 0; sc < 4; sc++) {
        #pragma unroll
        for (int q = 0; q < 4; q++) {
            const int qq = sc * 4 + q;
            const float4 cB = pB, cC = pC;
            float4 cd[4], cs[4];
            #pragma unroll
            for (int ee = 0; ee < 4; ee++) { cd[ee] = pd[ee]; cs[ee] = ps[ee]; }
            if (qq < 15) {
                const size_t off = (size_t)(qq + 1) * 1024;
                pB = *(const float4*)(bc + off);
                pC = *(const float4*)(bc + off + 4);
                const int t = (qq + 1) * 4;
                #pragma unroll
                for (int ee = 0; ee < 4; ee++) {
                    pd[ee] = *(const float4*)(dr[ee] + t);
                    ps[ee] = *(const float4*)(sr[ee] + t);
                }
            }
            #pragma unroll
            for (int ee = 0; ee < 4; ee++) {
                float a;
                a = exp2f(cd[ee].x*An[ee]); h[ee] = a*h[ee] + cs[ee].x*cB.x;
                part[ee][q*4+0][n] = h[ee]*cC.x;
                a = exp2f(cd[ee].y*An[ee]); h[ee] = a*h[ee] + cs[ee].y*cB.y;
                part[ee][q*4+1][n] = h[ee]*cC.y;
                a = exp2f(cd[ee].z*An[ee]); h[ee] = a*h[ee] + cs[ee].z*cB.z;
                part[ee][q*4+2][n] = h[ee]*cC.z;
                a = exp2f(cd[ee].w*An[ee]); h[ee] = a*h[ee] + cs[ee].w*cB.w;
                part[ee][q*4+3][n] = h[ee]*cC.w;
                cum[ee] += (cd[ee].x + cd[ee].y) + (cd[ee].z + cd[ee].w);
            }
        }
        __syncthreads();
        #pragma unroll
        for (int ee = 0; ee < 4; ee++) {
            float s0 = 0, s1 = 0, s2 = 0, s3 = 0;
            #pragma unroll
            for (int i = 0; i < 4; i++) {
                const float4 p = *(const float4*)(&part[ee][tl][jj*16 + i*4]);
                s0 += p.x; s1 += p.y; s2 += p.z; s3 += p.w;
            }
            float r = (s0 + s1) + (s2 + s3);
            r += __shfl_xor(r, 1); r += __shfl_xor(r, 2); r += __shfl_xor(r, 4);
            if (jj == 0) ybuf[ee][sc*16 + tl] = r;
        }
        __syncthreads();
    }
    {
        const int ee = n >> 5, tt = n & 31;
        float* yp = yT + (size_t)(e0 + ee) * BT + b * SS + t0;
        yp[tt] = ybuf[ee][tt];
        yp[tt + 32] = ybuf[ee][tt + 32];
    }
    #pragma unroll
    for (int ee = 0; ee < 4; ee++)
        hchain[(size_t)(((b * EE + e0 + ee) * GG) + g) * 128 + n] = h[ee];
    if (n == 0) {
        #pragma unroll
        for (int ee = 0; ee < 4; ee++)
            dsum[(b * EE + e0 + ee) * GG + g] = cum[ee];
    }
}

// ---------------- K4: cross-chunk correction (inline combine), 4 e's ---------
// grid = B*15*(EE/4) = 1920, block = 128 (n)
__global__ __launch_bounds__(128, 4) void k_scan_fix(
    const float* __restrict__ BC4, const float* __restrict__ deltaT,
    const float* __restrict__ Alog, const float* __restrict__ hchain,
    const float* __restrict__ dsum, float* __restrict__ yT)
{
    __shared__ float part[4][16][68];
    __shared__ float ybuf[4][CH];
    const int blk = blockIdx.x;
    const int wgid = (blk & 7) * 240 + (blk >> 3);   // bijective XCD swizzle
    const int eq = wgid & 63;
    const int r0 = wgid >> 6;       // 0..29
    const int b = r0 / 15;
    const int g = 1 + (r0 % 15);
    const int e0 = eq * 4;
    const int n = threadIdx.x;
    const int t0 = g * CH;

    float An[4], wst[4], D[4];
    #pragma unroll
    for (int ee = 0; ee < 4; ee++) {
        An[ee] = -__expf(Alog[(e0 + ee) * HH + n]) * LOG2E;
        wst[ee] = 0.0f; D[ee] = 0.0f;
    }
    {   // inline combine: chain h_end across chunks 0..g-1
        for (int gp = 0; gp < g; gp++) {
            #pragma unroll
            for (int ee = 0; ee < 4; ee++) {
                const float he = hchain[(size_t)(((b * EE + e0 + ee) * GG) + gp) * 128 + n];
                const float ds = dsum[(b * EE + e0 + ee) * GG + gp];
                wst[ee] = exp2f(An[ee] * ds) * wst[ee] + he;
            }
        }
    }
    const float* bc = BC4 + ((size_t)((b * 256 + g * 16) * 128 + n)) * 8;
    const float* dr[4];
    #pragma unroll
    for (int ee = 0; ee < 4; ee++)
        dr[ee] = deltaT + (size_t)(e0 + ee) * BT + b * SS + t0;

    float4 pC = *(const float4*)(bc + 4);
    float4 pd[4];
    #pragma unroll
    for (int ee = 0; ee < 4; ee++) pd[ee] = *(const float4*)dr[ee];

    const int tl = n >> 3, jj = n & 7;
    for (int sc = 0; sc < 4; sc++) {
        #pragma unroll
        for (int q = 0; q < 4; q++) {
            const int qq = sc * 4 + q;
            const float4 cC = pC;
            float4 cd[4];
            #pragma unroll
            for (int ee = 0; ee < 4; ee++) cd[ee] = pd[ee];
            if (qq < 15) {
                const size_t off = (size_t)(qq + 1) * 1024;
                pC = *(const float4*)(bc + off + 4);
                const int t = (qq + 1) * 4;
                #pragma unroll
                for (int ee = 0; ee < 4; ee++)
                    pd[ee] = *(const float4*)(dr[ee] + t);
            }
            #pragma unroll
            for (int ee = 0; ee < 4; ee++) {
                D[ee] += cd[ee].x; part[ee][q*4+0][n] = exp2f(An[ee]*D[ee]) * wst[ee] * cC.x;
                D[ee] += cd[ee].y; part[ee][q*4+1][n] = exp2f(An[ee]*D[ee]) * wst[ee] * cC.y;
                D[ee] += cd[ee].z; part[ee][q*4+2][n] = exp2f(An[ee]*D[ee]) * wst[ee] * cC.z;
                D[ee] += cd[ee].w; part[ee][q*4+3][n] = exp2f(An[ee]*D[ee]) * wst[ee] * cC.w;
            }
        }
        __syncthreads();
        #pragma unroll
        for (int ee = 0; ee < 4; ee++) {
            float s0 = 0, s1 = 0, s2 = 0, s3 = 0;
            #pragma unroll
            for (int i = 0; i < 4; i++) {
                const float4 p = *(const float4*)(&part[ee][tl][jj*16 + i*4]);
                s0 += p.x; s1 += p.y; s2 += p.z; s3 += p.w;
            }
            float r = (s0 + s1) + (s2 + s3);
            r += __shfl_xor(r, 1); r += __shfl_xor(r, 2); r += __shfl_xor(r, 4);
            if (jj == 0) ybuf[ee][sc*16 + tl] = r;
        }
        __syncthreads();
    }
    {
        const int ee = n >> 5, tt = n & 31;
        float* yp = yT + (size_t)(e0 + ee) * BT + b * SS + t0;
        yp[tt] += ybuf[ee][tt];
        yp[tt + 32] += ybuf[ee][tt + 32];
    }
}

// ---------------- K5: gate + out_proj + residual -> xres ---------------------
// 4-token tiles, grid 512, block 256. 4-way split-K, float4 weight loads.
__global__ __launch_bounds__(256) void k_gate(
    const float* __restrict__ yT, const float* __restrict__ xcT,
    const float* __restrict__ xz, const float* __restrict__ Dp,
    const float* __restrict__ ow, const float* __restrict__ ob,
    const float* __restrict__ resin, float* __restrict__ xres)
{
    __shared__ float gs[4][260];
    __shared__ float p2[3][4][132];
    const int bt0 = blockIdx.x * 4;
    const int tid = threadIdx.x;
    {
        const int e = tid;
        const float dp = Dp[e];
        const float4 y4 = *(const float4*)(yT + (size_t)e * BT + bt0);
        const float4 x4 = *(const float4*)(xcT + (size_t)e * BT + bt0);
        gs[0][e] = (y4.x + dp*x4.x) * silu_f(xz[(size_t)(bt0+0)*512 + 256 + e]);
        gs[1][e] = (y4.y + dp*x4.y) * silu_f(xz[(size_t)(bt0+1)*512 + 256 + e]);
        gs[2][e] = (y4.z + dp*x4.z) * silu_f(xz[(size_t)(bt0+2)*512 + 256 + e]);
        gs[3][e] = (y4.w + dp*x4.w) * silu_f(xz[(size_t)(bt0+3)*512 + 256 + e]);
    }
    __syncthreads();
    const int jj = tid & 31;             // 4 cols
    const int th = (tid >> 5) & 1;       // 2 tokens
    const int kh = tid >> 6;             // 4 e-quarters
    const int c0 = jj * 4, t0 = th * 2, eb = kh * 64;
    float4 acc0 = make_float4(0.f, 0.f, 0.f, 0.f);
    float4 acc1 = acc0;
    for (int e4 = 0; e4 < 16; e4++) {
        const int e = eb + e4 * 4;
        float4 wreg[4];
        #pragma unroll
        for (int kk = 0; kk < 4; kk++)
            wreg[kk] = *(const float4*)(ow + (size_t)(e + kk) * HH + c0);
        const float4 x0 = *(const float4*)(&gs[t0+0][e]);
        const float4 x1 = *(const float4*)(&gs[t0+1][e]);
        fma4(acc0, x0.x, wreg[0]); fma4(acc0, x0.y, wreg[1]);
        fma4(acc0, x0.z, wreg[2]); fma4(acc0, x0.w, wreg[3]);
        fma4(acc1, x1.x, wreg[0]); fma4(acc1, x1.y, wreg[1]);
        fma4(acc1, x1.z, wreg[2]); fma4(acc1, x1.w, wreg[3]);
    }
    if (kh > 0) {
        *(float4*)(&p2[kh-1][t0+0][c0]) = acc0;
        *(float4*)(&p2[kh-1][t0+1][c0]) = acc1;
    }
    __syncthreads();
    if (kh == 0) {
        const float4 bj = *(const float4*)(ob + c0);
        #pragma unroll
        for (int t = 0; t < 2; t++) {
            float4 a = t ? acc1 : acc0;
            #pragma unroll
            for (int s = 0; s < 3; s++) {
                const float4 p = *(const float4*)(&p2[s][t0+t][c0]);
                a.x += p.x; a.y += p.y; a.z += p.z; a.w += p.w;
            }
            const float4 rv = *(const float4*)(resin + (size_t)(bt0+t0+t) * HH + c0);
            a.x += bj.x + rv.x; a.y += bj.y + rv.y;
            a.z += bj.z + rv.z; a.w += bj.w + rv.w;
            *(float4*)(xres + (size_t)(bt0+t0+t) * HH + c0) = a;
        }
    }
}

// ---------------- K6: gate + out_proj + residual + final rmsnorm -> out ------
__global__ __launch_bounds__(256) void k_gate_final(
    const float* __restrict__ yT, const float* __restrict__ xcT,
    const float* __restrict__ xz, const float* __restrict__ Dp,
    const float* __restrict__ ow, const float* __restrict__ ob,
    const float* __restrict__ resin, const float* __restrict__ fw,
    float* __restrict__ out)
{
    __shared__ float gs[4][260];
    __shared__ float p2[3][4][132];
    __shared__ float rb[4][132];
    const int bt0 = blockIdx.x * 4;
    const int tid = threadIdx.x;
    {
        const int e = tid;
        const float dp = Dp[e];
        const float4 y4 = *(const float4*)(yT + (size_t)e * BT + bt0);
        const float4 x4 = *(const float4*)(xcT + (size_t)e * BT + bt0);
        gs[0][e] = (y4.x + dp*x4.x) * silu_f(xz[(size_t)(bt0+0)*512 + 256 + e]);
        gs[1][e] = (y4.y + dp*x4.y) * silu_f(xz[(size_t)(bt0+1)*512 + 256 + e]);
        gs[2][e] = (y4.z + dp*x4.z) * silu_f(xz[(size_t)(bt0+2)*512 + 256 + e]);
        gs[3][e] = (y4.w + dp*x4.w) * silu_f(xz[(size_t)(bt0+3)*512 + 256 + e]);
    }
    __syncthreads();
    const int jj = tid & 31;
    const int th = (tid >> 5) & 1;
    const int kh = tid >> 6;
    const int c0 = jj * 4, t0 = th * 2, eb = kh * 64;
    float4 acc0 = make_float4(0.f, 0.f, 0.f, 0.f);
    float4 acc1 = acc0;
    for (int e4 = 0; e4 < 16; e4++) {
        const int e = eb + e4 * 4;
        float4 wreg[4];
        #pragma unroll
        for (int kk = 0; kk < 4; kk++)
            wreg[kk] = *(const float4*)(ow + (size_t)(e + kk) * HH + c0);
        const float4 x0 = *(const float4*)(&gs[t0+0][e]);
        const float4 x1 = *(const float4*)(&gs[t0+1][e]);
        fma4(acc0, x0.x, wreg[0]); fma4(acc0, x0.y, wreg[1]);
        fma4(acc0, x0.z, wreg[2]); fma4(acc0, x0.w, wreg[3]);
        fma4(acc1, x1.x, wreg[0]); fma4(acc1, x1.y, wreg[1]);
        fma4(acc1, x1.z, wreg[2]); fma4(acc1, x1.w, wreg[3]);
    }
    if (kh > 0) {
        *(float4*)(&p2[kh-1][t0+0][c0]) = acc0;
        *(float4*)(&p2[kh-1][t0+1][c0]) = acc1;
    }
    __syncthreads();
    if (kh == 0) {
        const float4 bj = *(const float4*)(ob + c0);
        #pragma unroll
        for (int t = 0; t < 2; t++) {
            float4 a = t ? acc1 : acc0;
            #pragma unroll
            for (int s = 0; s < 3; s++) {
                const float4 p = *(const float4*)(&p2[s][t0+t][c0]);
                a.x += p.x; a.y += p.y; a.z += p.z; a.w += p.w;
            }
            const float4 rv = *(const float4*)(resin + (size_t)(bt0+t0+t) * HH + c0);
            a.x += bj.x + rv.x; a.y += bj.y + rv.y;
            a.z += bj.z + rv.z; a.w += bj.w + rv.w;
            *(float4*)(&rb[t0+t][c0]) = a;
        }
    }
    __syncthreads();
    {   // final rmsnorm: 64 lanes per token, 2 elems/lane
        const int t = tid >> 6, lane = tid & 63;
        const float2 v = *(const float2*)(&rb[t][lane * 2]);
        float ss = v.x*v.x + v.y*v.y;
        #pragma unroll
        for (int m = 32; m >= 1; m >>= 1) ss += __shfl_xor(ss, m);
        const float rs = rsqrtf(ss * (1.0f / HH) + EPS);
        const float2 w = *(const float2*)(fw + lane * 2);
        float2 o; o.x = v.x * rs * w.x; o.y = v.y * rs * w.y;
        *(float2*)(out + (size_t)(bt0 + t) * HH + lane * 2) = o;
    }
}

extern "C" void kernel_launch(void* const* d_in, const int* in_sizes, int n_in,
                              void* d_out, int out_size, void* d_ws, size_t ws_size,
                              hipStream_t stream)
{
    const float* x      = (const float*)d_in[0];
    const float* in_w   = (const float*)d_in[1];
    const float* in_b   = (const float*)d_in[2];
    const float* out_w  = (const float*)d_in[3];
    const float* out_b  = (const float*)d_in[4];
    const float* pl_w   = (const float*)d_in[5];
    const float* pl_b   = (const float*)d_in[6];
    const float* dt_w   = (const float*)d_in[7];
    const float* dt_b   = (const float*)d_in[8];
    const float* conv_w = (const float*)d_in[9];
    const float* conv_b = (const float*)d_in[10];
    const float* A_log  = (const float*)d_in[11];
    const float* Dp     = (const float*)d_in[12];
    const float* norm_w = (const float*)d_in[13];
    const float* fnw    = (const float*)d_in[14];

    float* ws     = (float*)d_ws;
    float* xres   = ws;                        // 262144
    float* xz     = xres   + 262144;           // 1048576 (xc cols 0..255, z 256..511)
    float* xcT    = xz     + 1048576;          // 524288
    float* BC4    = xcT    + 524288;           // 524288
    float* deltaT = BC4    + 524288;           // 524288
    float* sT     = deltaT + 524288;           // 524288
    float* yT     = sT     + 524288;           // 524288
    float* hchain = yT     + 524288;           // 1048576
    float* dsum   = hchain + 1048576;          // 8192
    float* Wdt    = dsum   + 8192;             // 131072
    float* bdt    = Wdt    + 131072;           // 512

    k_wdt<<<2*4, 256, 0, stream>>>(pl_w, pl_b, dt_w, dt_b, Wdt, bdt);

    for (int l = 0; l < LL; l++) {
        const float* resin = (l == 0) ? x : xres;
        k_ninp<<<(BT/8)*2, 256, 0, stream>>>(
            resin, in_w + (size_t)l*HH*2*EE, in_b + (size_t)l*2*EE,
            norm_w + (size_t)l*HH, xz);
        k_cbd<<<(BT/8)*2, 256, 0, stream>>>(
            xz, conv_w + (size_t)l*EE*KK, conv_b + (size_t)l*EE,
            pl_w + (size_t)l*EE*NJ, pl_b + (size_t)l*NJ,
            Wdt + (size_t)l*EE*EE, bdt + (size_t)l*EE,
            xcT, BC4, deltaT, sT);
        k_scan_local<<<BB*GG*(EE/4), 128, 0, stream>>>(
            BC4, deltaT, sT, A_log + (size_t)l*EE*HH, yT, hchain, dsum);
        k_scan_fix<<<BB*(GG-1)*(EE/4), 128, 0, stream>>>(
            BC4, deltaT, A_log + (size_t)l*EE*HH, hchain, dsum, yT);
        if (l < LL - 1) {
            k_gate<<<BT/4, 256, 0, stream>>>(
                yT, xcT, xz, Dp + (size_t)l*EE,
                out_w + (size_t)l*EE*HH, out_b + (size_t)l*HH, resin, xres);
        } else {
            k_gate_final<<<BT/4, 256, 0, stream>>>(
                yT, xcT, xz, Dp + (size_t)l*EE,
                out_w + (size_t)l*EE*HH, out_b + (size_t)l*HH, xres,
                fnw, (float*)d_out);
        }
    }
}